// Round 4
// baseline (667.237 us; speedup 1.0000x reference)
//
#include <hip/hip_runtime.h>
#include <cmath>

#define HW 256
#define NIMG 48
#define NCH 3
#define NPLANE (NIMG * NCH)
#define STRIP 19          // output rows per block; 144*14 = 2016 blocks ~ 7.9/CU
#define NSTRIP 14         // 14*19 = 266 >= 256 -> ONE residency round at 8 blk/CU
#define NIN (STRIP + 10)  // 29 input rows per block
#define CH 8              // rows staged per barrier (LDS chunk)
#define NCHUNK 4          // ceil(29/8)
#define NSLOT 64          // ws accumulator slots

// ws doubles: ws[0..63] partial sums of (10*d + 10*l1 + 5*lw)
__global__ void zero_ws_kernel(double* ws) {
    if (threadIdx.x < NSLOT) ws[threadIdx.x] = 0.0;
}

// ---------------------------------------------------------------------------
// Fused SSIM + L1 + weighted-L1. One block = 19-row strip of one (n,c) plane.
// Separable 11x11 Gaussian: h-pass from LDS (8 rows staged per barrier),
// v-pass via an 11-slot register ring with compile-time cyclic indexing.
// Occupancy design: VGPR<=64 (ring=55 VGPR; uniform g[] lives in SGPRs) -> 8
// waves/SIMD band. LDS <20KB (spt 8 rows) -> 8 blocks/CU. Grid 2016 = 7.9
// blocks/CU -> whole grid resident in one round.
// Chunk loop MUST be unrolled: ring slot i%11 needs compile-time i with CH=8.
// Round-1 lesson: no register prefetch (spills at 64-VGPR edge).
// Round-3 lesson: sbbs/svalids are written by x<3 and register-copied by ALL
// threads -> needs a __syncthreads() BEFORE the bb/sv copies (race caused
// absmax=1.5 fail).
// ---------------------------------------------------------------------------
__launch_bounds__(256, 8)
__global__ void fused_kernel(const float* __restrict__ pred,
                             const float* __restrict__ target,
                             const float* __restrict__ lmk,
                             double* __restrict__ ws)
{
    const int plane = blockIdx.x;          // n*3 + c
    const int n     = plane / 3;
    const int r0    = blockIdx.y * STRIP;
    const int x     = threadIdx.x;

    __shared__ float2 spt[CH][HW + 10];    // (p,t) rows, 5-wide zero pads
    __shared__ float  sxc[STRIP][24];      // crossing x per (row, edge)
    __shared__ float  slm[48];             // landmarks 36..59 (x,y)
    __shared__ float  sbbs[12];            // per poly: xmin,xmax,ymin,ymax
    __shared__ float  svalids[3];
    __shared__ float  red[12];

    // Gaussian weights (same fp32 math as reference); thread-uniform -> SGPRs
    float g[11];
    {
        float gs = 0.f;
#pragma unroll
        for (int i = 0; i < 11; ++i) {
            float c = (float)i - 5.0f;
            g[i] = expf(-c * c / 4.5f);
            gs += g[i];
        }
#pragma unroll
        for (int i = 0; i < 11; ++i) g[i] /= gs;
    }

    // ---- prologue: landmarks, pads (once), bboxes, crossing table ----------
    if (x < 48) slm[x] = lmk[n * 136 + 72 + x];
    if (x < 5) {
#pragma unroll
        for (int t = 0; t < CH; ++t) {
            spt[t][x]       = make_float2(0.f, 0.f);
            spt[t][261 + x] = make_float2(0.f, 0.f);
        }
    }
    __syncthreads();   // slm ready

    if (x < 3) {
        const int s0 = (x == 0) ? 0 : (x == 1) ? 6 : 12;
        const int L  = (x == 2) ? 12 : 6;
        float xmn = 3e38f, xmx = -3e38f, ymn = 3e38f, ymx = -3e38f;
        for (int i = 0; i < L; ++i) {
            float px = slm[2 * (s0 + i)], py = slm[2 * (s0 + i) + 1];
            xmn = fminf(xmn, px); xmx = fmaxf(xmx, px);
            ymn = fminf(ymn, py); ymx = fmaxf(ymx, py);
        }
        xmn = floorf(xmn); xmx = floorf(xmx); ymn = floorf(ymn); ymx = floorf(ymx);
        sbbs[4 * x + 0] = xmn; sbbs[4 * x + 1] = xmx;
        sbbs[4 * x + 2] = ymn; sbbs[4 * x + 3] = ymx;
        svalids[x] = (xmn >= 0.f && ymn >= 0.f && xmx < 256.f && ymx < 256.f) ? 1.f : 0.f;
    }

#pragma unroll
    for (int u = 0; u < (STRIP * 24 + 255) / 256; ++u) {
        int idx = x + 256 * u;
        if (idx < STRIP * 24) {
            int r = idx / 24, e = idx - r * 24;
            float Y = (float)(r0 + r);
            const int s0 = (e < 6) ? 0 : (e < 12) ? 6 : 12;
            const int L  = (e < 12) ? 6 : 12;
            int il = e - s0;
            int i2 = (il + 1 == L) ? 0 : il + 1;
            float x1 = slm[2 * (s0 + il)], y1 = slm[2 * (s0 + il) + 1];
            float x2 = slm[2 * (s0 + i2)], y2 = slm[2 * (s0 + i2) + 1];
            bool crossing = (y1 > Y) != (y2 > Y);
            // exact reference fp32 expression order
            float xc = (x2 - x1) * (Y - y1) / (y2 - y1 + 1e-6f) + x1;
            sxc[r][e] = crossing ? xc : -3e38f;
        }
    }
    __syncthreads();   // sbbs/svalids/sxc visible to ALL threads (round-3 fix)

    float bb[12], sv[3];
#pragma unroll
    for (int q = 0; q < 12; ++q) bb[q] = sbbs[q];
#pragma unroll
    for (int q = 0; q < 3; ++q) sv[q] = svalids[q];

    const float* __restrict__ pp = pred   + (size_t)plane * (HW * HW);
    const float* __restrict__ tp = target + (size_t)plane * (HW * HW);

    // h-conv moment ring: slot = input_iter % 11, all indices compile-time
    float ring[11][5];
#pragma unroll
    for (int s = 0; s < 11; ++s)
#pragma unroll
        for (int q = 0; q < 5; ++q) ring[s][q] = 0.f;

    float acc = 0.f, accl1 = 0.f, acclw = 0.f;
    const float X = (float)x;

    // input rows r0-5 .. r0+23: 4 chunks of <=8 rows; unrolled so that every
    // i = CH*c + t is a compile-time constant (ring slots, section guards).
#pragma unroll
    for (int c = 0; c < NCHUNK; ++c) {
        __syncthreads();   // previous chunk's spt reads complete
#pragma unroll
        for (int t = 0; t < CH; ++t) {
            const int i = CH * c + t;
            if (i < NIN) {
                int r_in = r0 - 5 + i;
                float pv = 0.f, tv = 0.f;
                if (r_in >= 0 && r_in < HW) {
                    pv = pp[r_in * HW + x];
                    tv = tp[r_in * HW + x];
                }
                spt[t][x + 5] = make_float2(pv, tv);
            }
        }
        __syncthreads();

#pragma unroll
        for (int t = 0; t < CH; ++t) {
            const int i = CH * c + t;         // compile-time constant
            if (i >= NIN) continue;           // pruned at compile time
            const int r_in = r0 - 5 + i;

            // horizontal conv of the 5 moments; capture center tap (k==5)
            float h0 = 0.f, h1 = 0.f, h2 = 0.f, h3 = 0.f, h4 = 0.f;
            float2 center;
#pragma unroll
            for (int k = 0; k < 11; ++k) {
                float2 v = spt[t][x + k];
                if (k == 5) center = v;
                float w = g[k];
                float wp = w * v.x, wt = w * v.y;
                h0 += wp;
                h1 += wt;
                h2 = fmaf(wp, v.x, h2);
                h3 = fmaf(wt, v.y, h3);
                h4 = fmaf(wp, v.y, h4);
            }
            ring[i % 11][0] = h0; ring[i % 11][1] = h1; ring[i % 11][2] = h2;
            ring[i % 11][3] = h3; ring[i % 11][4] = h4;

            // ---- L1 + weighted L1 for input row r_in (each row exactly once)
            if (i >= 5 && i < 5 + STRIP) {        // compile-time
                if (r_in < HW) {                  // runtime, wave-uniform
                    float ad = fabsf(center.x - center.y);
                    accl1 += ad;
                    float Y = (float)r_in;
                    float wgt = 1.f;
                    bool any0 = (sv[0] != 0.f) && (Y >= bb[2])  && (Y < bb[3]);
                    bool any1 = (sv[1] != 0.f) && (Y >= bb[6])  && (Y < bb[7]);
                    bool any2 = (sv[2] != 0.f) && (Y >= bb[10]) && (Y < bb[11]);
                    if (any0 || any1 || any2) {   // wave-uniform branch
                        const float* xc = sxc[i - 5];
                        int c0 = 0, c1 = 0, c2 = 0;
#pragma unroll
                        for (int e = 0; e < 6; ++e)   c0 += (X < xc[e]) ? 1 : 0;
#pragma unroll
                        for (int e = 6; e < 12; ++e)  c1 += (X < xc[e]) ? 1 : 0;
#pragma unroll
                        for (int e = 12; e < 24; ++e) c2 += (X < xc[e]) ? 1 : 0;
                        if (any0 && (c0 & 1) && X >= bb[0] && X < bb[1]) wgt += 3.f;
                        if (any1 && (c1 & 1) && X >= bb[4] && X < bb[5]) wgt += 3.f;
                        if (any2 && (c2 & 1) && X >= bb[8] && X < bb[9]) wgt += 2.f;
                    }
                    acclw += wgt * ad;
                }
            }

            // ---- SSIM output row r_out = r0 + i - 10 ------------------------
            if (i >= 10) {                        // compile-time (i < 10+STRIP always)
                const int r_out = r0 + (i - 10);
                if (r_out < HW) {                 // runtime, wave-uniform
                    float mux = 0.f, muy = 0.f, exx = 0.f, eyy = 0.f, exy = 0.f;
#pragma unroll
                    for (int j = 0; j < 11; ++j) {
                        const int s = (i + 1 + j) % 11;   // compile-time
                        float w = g[j];
                        mux = fmaf(w, ring[s][0], mux);
                        muy = fmaf(w, ring[s][1], muy);
                        exx = fmaf(w, ring[s][2], exx);
                        eyy = fmaf(w, ring[s][3], eyy);
                        exy = fmaf(w, ring[s][4], exy);
                    }
                    float sx  = exx - mux * mux;
                    float sy  = eyy - muy * muy;
                    float sxy = exy - mux * muy;
                    const float C1 = 1e-4f, C2 = 9e-4f;
                    float num = (2.f * mux * muy + C1) * (2.f * sxy + C2);
                    float den = (mux * mux + muy * muy + C1) * (sx + sy + C2);
                    acc += 0.5f * (1.f - num / (den + 1e-8f));
                }
            }
        }
    }

    // ---- block reduction ---------------------------------------------------
#pragma unroll
    for (int off = 32; off > 0; off >>= 1) {
        acc   += __shfl_down(acc, off, 64);
        accl1 += __shfl_down(accl1, off, 64);
        acclw += __shfl_down(acclw, off, 64);
    }
    if ((x & 63) == 0) {
        int w = x >> 6;
        red[w] = acc; red[4 + w] = accl1; red[8 + w] = acclw;
    }
    __syncthreads();
    if (x == 0) {
        double s = 10.0 * ((double)red[0] + red[1] + red[2]  + red[3])
                 + 10.0 * ((double)red[4] + red[5] + red[6]  + red[7])
                 +  5.0 * ((double)red[8] + red[9] + red[10] + red[11]);
        atomicAdd(&ws[(blockIdx.y * NPLANE + blockIdx.x) & (NSLOT - 1)], s);
    }
}

// ---------------------------------------------------------------------------
__global__ void final_kernel(const double* __restrict__ ws, float* __restrict__ out) {
    double v = ws[threadIdx.x];
#pragma unroll
    for (int off = 32; off > 0; off >>= 1)
        v += __shfl_down(v, off, 64);
    if (threadIdx.x == 0) {
        const double denom = (double)NIMG * NCH * HW * HW;
        out[0] = (float)(v / denom);
    }
}

// ---------------------------------------------------------------------------
extern "C" void kernel_launch(void* const* d_in, const int* in_sizes, int n_in,
                              void* d_out, int out_size, void* d_ws, size_t ws_size,
                              hipStream_t stream)
{
    const float* pred   = (const float*)d_in[0];
    const float* target = (const float*)d_in[1];
    const float* lmk    = (const float*)d_in[2];
    float* out  = (float*)d_out;
    double* ws  = (double*)d_ws;

    hipLaunchKernelGGL(zero_ws_kernel, dim3(1), dim3(64), 0, stream, ws);
    hipLaunchKernelGGL(fused_kernel, dim3(NPLANE, NSTRIP), dim3(256), 0, stream,
                       pred, target, lmk, ws);
    hipLaunchKernelGGL(final_kernel, dim3(1), dim3(64), 0, stream, ws, out);
}

// Round 5
// 387.142 us; speedup vs baseline: 1.7235x; 1.7235x over previous
//
#include <hip/hip_runtime.h>
#include <cmath>

#define HW 256
#define NIMG 48
#define NCH 3
#define NPLANE (NIMG * NCH)
#define STRIP 19          // output rows per block; 144*14 = 2016 blocks ~ 7.9/CU
#define NSTRIP 14         // 14*19 = 266 >= 256 -> ONE residency round at 8 blk/CU
#define NIN (STRIP + 10)  // 29 input rows per block
#define CH 8              // rows staged per barrier (LDS chunk)
#define NCHUNK 4          // ceil(29/8)
#define NSLOT 64          // ws accumulator slots

// ws doubles: ws[0..63] partial sums of (10*d + 10*l1 + 5*lw)
__global__ void zero_ws_kernel(double* ws) {
    if (threadIdx.x < NSLOT) ws[threadIdx.x] = 0.0;
}

// ---------------------------------------------------------------------------
// Fused SSIM + L1 + weighted-L1. One block = 19-row strip of one (n,c) plane.
// Separable 11x11 Gaussian: h-pass from LDS (8 rows staged per barrier),
// v-pass via an 11-slot register ring with compile-time cyclic indexing.
//
// Occupancy design: ring=55 VGPR dominates; bb/sv register copies REMOVED
// (round-4 lesson) -> fits 64-VGPR band -> 8 waves/SIMD. LDS 19.5KB -> 8
// blocks/CU. Grid 2016 = 7.9 blocks/CU (82% occupancy verified in round 4).
//
// Compiler model note (rounds 1+4, journal-worthy): clang's gfx950
// __launch_bounds__(256,w) caps VGPR at 256/w (pool model = 256/EU), which is
// HALF the measured HW pool (m69: 8 waves/SIMD at 64 VGPR). (256,8) -> 32
// VGPR -> 849 MB scratch spill. Use (256,4): cap 64 = exactly the HW 8-wave
// band. Hot-path poly y-tests precomputed into srowflag (1 LDS read/row);
// x-ranges read from sbbs LDS inside the rare wave-uniform branch.
// Round-3 lesson: barrier between sbbs writes (x<3) and any cross-thread read.
// ---------------------------------------------------------------------------
__launch_bounds__(256, 4)
__global__ void fused_kernel(const float* __restrict__ pred,
                             const float* __restrict__ target,
                             const float* __restrict__ lmk,
                             double* __restrict__ ws)
{
    const int plane = blockIdx.x;          // n*3 + c
    const int n     = plane / 3;
    const int r0    = blockIdx.y * STRIP;
    const int x     = threadIdx.x;

    __shared__ float2 spt[CH][HW + 10];    // (p,t) rows, 5-wide zero pads
    __shared__ float  sxc[STRIP][24];      // crossing x per (row, edge)
    __shared__ int    srowflag[STRIP];     // bit p: poly p valid && row in y-range
    __shared__ float  slm[48];             // landmarks 36..59 (x,y)
    __shared__ float  sbbs[12];            // per poly: xmin,xmax,ymin,ymax
    __shared__ float  svalids[3];
    __shared__ float  red[12];

    // Gaussian weights (same fp32 math as reference); thread-uniform -> SGPRs
    float g[11];
    {
        float gs = 0.f;
#pragma unroll
        for (int i = 0; i < 11; ++i) {
            float c = (float)i - 5.0f;
            g[i] = expf(-c * c / 4.5f);
            gs += g[i];
        }
#pragma unroll
        for (int i = 0; i < 11; ++i) g[i] /= gs;
    }

    // ---- prologue ----------------------------------------------------------
    if (x < 48) slm[x] = lmk[n * 136 + 72 + x];
    if (x < 5) {
#pragma unroll
        for (int t = 0; t < CH; ++t) {
            spt[t][x]       = make_float2(0.f, 0.f);
            spt[t][261 + x] = make_float2(0.f, 0.f);
        }
    }
    __syncthreads();   // slm ready

    if (x < 3) {
        const int s0 = (x == 0) ? 0 : (x == 1) ? 6 : 12;
        const int L  = (x == 2) ? 12 : 6;
        float xmn = 3e38f, xmx = -3e38f, ymn = 3e38f, ymx = -3e38f;
        for (int i = 0; i < L; ++i) {
            float px = slm[2 * (s0 + i)], py = slm[2 * (s0 + i) + 1];
            xmn = fminf(xmn, px); xmx = fmaxf(xmx, px);
            ymn = fminf(ymn, py); ymx = fmaxf(ymx, py);
        }
        xmn = floorf(xmn); xmx = floorf(xmx); ymn = floorf(ymn); ymx = floorf(ymx);
        sbbs[4 * x + 0] = xmn; sbbs[4 * x + 1] = xmx;
        sbbs[4 * x + 2] = ymn; sbbs[4 * x + 3] = ymx;
        svalids[x] = (xmn >= 0.f && ymn >= 0.f && xmx < 256.f && ymx < 256.f) ? 1.f : 0.f;
    }

#pragma unroll
    for (int u = 0; u < (STRIP * 24 + 255) / 256; ++u) {
        int idx = x + 256 * u;
        if (idx < STRIP * 24) {
            int r = idx / 24, e = idx - r * 24;
            float Y = (float)(r0 + r);
            const int s0 = (e < 6) ? 0 : (e < 12) ? 6 : 12;
            const int L  = (e < 12) ? 6 : 12;
            int il = e - s0;
            int i2 = (il + 1 == L) ? 0 : il + 1;
            float x1 = slm[2 * (s0 + il)], y1 = slm[2 * (s0 + il) + 1];
            float x2 = slm[2 * (s0 + i2)], y2 = slm[2 * (s0 + i2) + 1];
            bool crossing = (y1 > Y) != (y2 > Y);
            // exact reference fp32 expression order
            float xc = (x2 - x1) * (Y - y1) / (y2 - y1 + 1e-6f) + x1;
            sxc[r][e] = crossing ? xc : -3e38f;
        }
    }
    __syncthreads();   // sbbs/svalids visible (round-3 fix); sxc ready

    if (x < STRIP) {
        float Y = (float)(r0 + x);
        int f = 0;
        if (svalids[0] != 0.f && Y >= sbbs[2]  && Y < sbbs[3])  f |= 1;
        if (svalids[1] != 0.f && Y >= sbbs[6]  && Y < sbbs[7])  f |= 2;
        if (svalids[2] != 0.f && Y >= sbbs[10] && Y < sbbs[11]) f |= 4;
        srowflag[x] = f;
    }
    __syncthreads();   // srowflag ready

    const float* __restrict__ pp = pred   + (size_t)plane * (HW * HW);
    const float* __restrict__ tp = target + (size_t)plane * (HW * HW);

    // h-conv moment ring: slot = input_iter % 11, all indices compile-time
    float ring[11][5];
#pragma unroll
    for (int s = 0; s < 11; ++s)
#pragma unroll
        for (int q = 0; q < 5; ++q) ring[s][q] = 0.f;

    float acc = 0.f, accl1 = 0.f, acclw = 0.f;
    const float X = (float)x;

    // input rows r0-5 .. r0+23: 4 chunks of <=8 rows; unrolled so that every
    // i = CH*c + t is a compile-time constant (ring slots, section guards).
#pragma unroll
    for (int c = 0; c < NCHUNK; ++c) {
        __syncthreads();   // previous chunk's spt reads complete
#pragma unroll
        for (int t = 0; t < CH; ++t) {
            const int i = CH * c + t;
            if (i < NIN) {
                int r_in = r0 - 5 + i;
                float pv = 0.f, tv = 0.f;
                if (r_in >= 0 && r_in < HW) {
                    pv = pp[r_in * HW + x];
                    tv = tp[r_in * HW + x];
                }
                spt[t][x + 5] = make_float2(pv, tv);
            }
        }
        __syncthreads();

#pragma unroll
        for (int t = 0; t < CH; ++t) {
            const int i = CH * c + t;         // compile-time constant
            if (i >= NIN) continue;           // pruned at compile time
            const int r_in = r0 - 5 + i;

            // horizontal conv of the 5 moments; capture center tap (k==5)
            float h0 = 0.f, h1 = 0.f, h2 = 0.f, h3 = 0.f, h4 = 0.f;
            float2 center;
#pragma unroll
            for (int k = 0; k < 11; ++k) {
                float2 v = spt[t][x + k];
                if (k == 5) center = v;
                float w = g[k];
                float wp = w * v.x, wt = w * v.y;
                h0 += wp;
                h1 += wt;
                h2 = fmaf(wp, v.x, h2);
                h3 = fmaf(wt, v.y, h3);
                h4 = fmaf(wp, v.y, h4);
            }
            ring[i % 11][0] = h0; ring[i % 11][1] = h1; ring[i % 11][2] = h2;
            ring[i % 11][3] = h3; ring[i % 11][4] = h4;

            // ---- L1 + weighted L1 for input row r_in (each row exactly once)
            if (i >= 5 && i < 5 + STRIP) {        // compile-time
                if (r_in < HW) {                  // runtime, wave-uniform
                    float ad = fabsf(center.x - center.y);
                    accl1 += ad;
                    float wgt = 1.f;
                    const int flags = srowflag[i - 5];   // broadcast LDS read
                    if (flags) {                  // wave-uniform branch
                        const float* xc = sxc[i - 5];
                        int c0 = 0, c1 = 0, c2 = 0;
#pragma unroll
                        for (int e = 0; e < 6; ++e)   c0 += (X < xc[e]) ? 1 : 0;
#pragma unroll
                        for (int e = 6; e < 12; ++e)  c1 += (X < xc[e]) ? 1 : 0;
#pragma unroll
                        for (int e = 12; e < 24; ++e) c2 += (X < xc[e]) ? 1 : 0;
                        if ((flags & 1) && (c0 & 1) && X >= sbbs[0] && X < sbbs[1]) wgt += 3.f;
                        if ((flags & 2) && (c1 & 1) && X >= sbbs[4] && X < sbbs[5]) wgt += 3.f;
                        if ((flags & 4) && (c2 & 1) && X >= sbbs[8] && X < sbbs[9]) wgt += 2.f;
                    }
                    acclw += wgt * ad;
                }
            }

            // ---- SSIM output row r_out = r0 + i - 10 ------------------------
            if (i >= 10) {                        // compile-time (i < 10+STRIP always)
                const int r_out = r0 + (i - 10);
                if (r_out < HW) {                 // runtime, wave-uniform
                    float mux = 0.f, muy = 0.f, exx = 0.f, eyy = 0.f, exy = 0.f;
#pragma unroll
                    for (int j = 0; j < 11; ++j) {
                        const int s = (i + 1 + j) % 11;   // compile-time
                        float w = g[j];
                        mux = fmaf(w, ring[s][0], mux);
                        muy = fmaf(w, ring[s][1], muy);
                        exx = fmaf(w, ring[s][2], exx);
                        eyy = fmaf(w, ring[s][3], eyy);
                        exy = fmaf(w, ring[s][4], exy);
                    }
                    float sx  = exx - mux * mux;
                    float sy  = eyy - muy * muy;
                    float sxy = exy - mux * muy;
                    const float C1 = 1e-4f, C2 = 9e-4f;
                    float num = (2.f * mux * muy + C1) * (2.f * sxy + C2);
                    float den = (mux * mux + muy * muy + C1) * (sx + sy + C2);
                    acc += 0.5f * (1.f - num / (den + 1e-8f));
                }
            }
        }
    }

    // ---- block reduction ---------------------------------------------------
#pragma unroll
    for (int off = 32; off > 0; off >>= 1) {
        acc   += __shfl_down(acc, off, 64);
        accl1 += __shfl_down(accl1, off, 64);
        acclw += __shfl_down(acclw, off, 64);
    }
    if ((x & 63) == 0) {
        int w = x >> 6;
        red[w] = acc; red[4 + w] = accl1; red[8 + w] = acclw;
    }
    __syncthreads();
    if (x == 0) {
        double s = 10.0 * ((double)red[0] + red[1] + red[2]  + red[3])
                 + 10.0 * ((double)red[4] + red[5] + red[6]  + red[7])
                 +  5.0 * ((double)red[8] + red[9] + red[10] + red[11]);
        atomicAdd(&ws[(blockIdx.y * NPLANE + blockIdx.x) & (NSLOT - 1)], s);
    }
}

// ---------------------------------------------------------------------------
__global__ void final_kernel(const double* __restrict__ ws, float* __restrict__ out) {
    double v = ws[threadIdx.x];
#pragma unroll
    for (int off = 32; off > 0; off >>= 1)
        v += __shfl_down(v, off, 64);
    if (threadIdx.x == 0) {
        const double denom = (double)NIMG * NCH * HW * HW;
        out[0] = (float)(v / denom);
    }
}

// ---------------------------------------------------------------------------
extern "C" void kernel_launch(void* const* d_in, const int* in_sizes, int n_in,
                              void* d_out, int out_size, void* d_ws, size_t ws_size,
                              hipStream_t stream)
{
    const float* pred   = (const float*)d_in[0];
    const float* target = (const float*)d_in[1];
    const float* lmk    = (const float*)d_in[2];
    float* out  = (float*)d_out;
    double* ws  = (double*)d_ws;

    hipLaunchKernelGGL(zero_ws_kernel, dim3(1), dim3(64), 0, stream, ws);
    hipLaunchKernelGGL(fused_kernel, dim3(NPLANE, NSTRIP), dim3(256), 0, stream,
                       pred, target, lmk, ws);
    hipLaunchKernelGGL(final_kernel, dim3(1), dim3(64), 0, stream, ws, out);
}

// Round 6
// 169.567 us; speedup vs baseline: 3.9349x; 2.2831x over previous
//
#include <hip/hip_runtime.h>
#include <cmath>

#define HW 256
#define NIMG 48
#define NCH 3
#define NPLANE (NIMG * NCH)
#define STRIP 26          // output rows per block; 144*10 = 1440 blocks = 5.6/CU
#define NSTRIP 10         // 10*26 = 260 >= 256 -> ONE residency round at 6 blk/CU
#define NIN (STRIP + 10)  // 36 input rows per block
#define NCHUNK 4          // ceil(36/11) chunks of 11
#define NSLOT 64          // ws accumulator slots

// ws doubles: ws[0..63] partial sums of (10*d + 10*l1 + 5*lw)
__global__ void zero_ws_kernel(double* ws) {
    if (threadIdx.x < NSLOT) ws[threadIdx.x] = 0.0;
}

// ---------------------------------------------------------------------------
// Fused SSIM + L1 + weighted-L1. One block = 26-row strip of one (n,c) plane.
// Separable 11x11 Gaussian: h-pass from LDS (11 rows staged per barrier),
// v-pass via an 11-slot register ring (slot = t, compile-time, since chunks
// are exactly 11 rows -> runtime chunk loop stays compact).
//
// STRUCTURE RULE (rounds 1/4/5, 3 data points): any explicit VGPR cap
// (launch_bounds 2nd arg) combined with a large unrolled body => scratch
// spills (849MB / 510MB WRITE_SIZE observed). The ONLY no-spill config is
// this compact CH=11 runtime-chunk-loop + plain __launch_bounds__(256)
// (round 2: VGPR=64, WRITE 31.5KB). So: dials moved here are LDS (25.7KB
// -> 6 blocks/CU) and grid (1440 = 5.625/CU, one residency round), NOT
// register pressure. srowflag path (round-5, verified) gives the allocator
// 15 regs of slack instead of demanding a cap.
// Round-3 lesson: barrier between sbbs writes (x<3) and cross-thread reads.
// ---------------------------------------------------------------------------
__launch_bounds__(256)
__global__ void fused_kernel(const float* __restrict__ pred,
                             const float* __restrict__ target,
                             const float* __restrict__ lmk,
                             double* __restrict__ ws)
{
    const int plane = blockIdx.x;          // n*3 + c
    const int n     = plane / 3;
    const int r0    = blockIdx.y * STRIP;
    const int x     = threadIdx.x;

    __shared__ float2 spt[11][HW + 10];    // (p,t) rows, 5-wide zero pads
    __shared__ float  sxc[STRIP][24];      // crossing x per (row, edge)
    __shared__ int    srowflag[STRIP];     // bit p: poly p valid && row in y-range
    __shared__ float  slm[48];             // landmarks 36..59 (x,y)
    __shared__ float  sbbs[12];            // per poly: xmin,xmax,ymin,ymax
    __shared__ float  svalids[3];
    __shared__ float  red[12];

    // Gaussian weights (same fp32 math as reference); thread-uniform -> SGPRs
    float g[11];
    {
        float gs = 0.f;
#pragma unroll
        for (int i = 0; i < 11; ++i) {
            float c = (float)i - 5.0f;
            g[i] = expf(-c * c / 4.5f);
            gs += g[i];
        }
#pragma unroll
        for (int i = 0; i < 11; ++i) g[i] /= gs;
    }

    // ---- prologue ----------------------------------------------------------
    if (x < 48) slm[x] = lmk[n * 136 + 72 + x];
    if (x < 5) {
#pragma unroll
        for (int t = 0; t < 11; ++t) {
            spt[t][x]       = make_float2(0.f, 0.f);
            spt[t][261 + x] = make_float2(0.f, 0.f);
        }
    }
    __syncthreads();   // slm ready

    if (x < 3) {
        const int s0 = (x == 0) ? 0 : (x == 1) ? 6 : 12;
        const int L  = (x == 2) ? 12 : 6;
        float xmn = 3e38f, xmx = -3e38f, ymn = 3e38f, ymx = -3e38f;
        for (int i = 0; i < L; ++i) {
            float px = slm[2 * (s0 + i)], py = slm[2 * (s0 + i) + 1];
            xmn = fminf(xmn, px); xmx = fmaxf(xmx, px);
            ymn = fminf(ymn, py); ymx = fmaxf(ymx, py);
        }
        xmn = floorf(xmn); xmx = floorf(xmx); ymn = floorf(ymn); ymx = floorf(ymx);
        sbbs[4 * x + 0] = xmn; sbbs[4 * x + 1] = xmx;
        sbbs[4 * x + 2] = ymn; sbbs[4 * x + 3] = ymx;
        svalids[x] = (xmn >= 0.f && ymn >= 0.f && xmx < 256.f && ymx < 256.f) ? 1.f : 0.f;
    }

#pragma unroll
    for (int u = 0; u < (STRIP * 24 + 255) / 256; ++u) {
        int idx = x + 256 * u;
        if (idx < STRIP * 24) {
            int r = idx / 24, e = idx - r * 24;
            float Y = (float)(r0 + r);
            const int s0 = (e < 6) ? 0 : (e < 12) ? 6 : 12;
            const int L  = (e < 12) ? 6 : 12;
            int il = e - s0;
            int i2 = (il + 1 == L) ? 0 : il + 1;
            float x1 = slm[2 * (s0 + il)], y1 = slm[2 * (s0 + il) + 1];
            float x2 = slm[2 * (s0 + i2)], y2 = slm[2 * (s0 + i2) + 1];
            bool crossing = (y1 > Y) != (y2 > Y);
            // exact reference fp32 expression order
            float xc = (x2 - x1) * (Y - y1) / (y2 - y1 + 1e-6f) + x1;
            sxc[r][e] = crossing ? xc : -3e38f;
        }
    }
    __syncthreads();   // sbbs/svalids visible to all (round-3 fix); sxc ready

    if (x < STRIP) {
        float Y = (float)(r0 + x);
        int f = 0;
        if (svalids[0] != 0.f && Y >= sbbs[2]  && Y < sbbs[3])  f |= 1;
        if (svalids[1] != 0.f && Y >= sbbs[6]  && Y < sbbs[7])  f |= 2;
        if (svalids[2] != 0.f && Y >= sbbs[10] && Y < sbbs[11]) f |= 4;
        srowflag[x] = f;
    }
    // no barrier needed here beyond the chunk loop's first __syncthreads()?
    // srowflag is read by ALL threads in the compute phase, which is after
    // the chunk-0 staging barrier -- but staging barrier #1 comes BEFORE
    // srowflag writes complete only if ordered; keep an explicit barrier:
    __syncthreads();   // srowflag ready for all

    const float* __restrict__ pp = pred   + (size_t)plane * (HW * HW);
    const float* __restrict__ tp = target + (size_t)plane * (HW * HW);

    // h-conv moment ring: slot = t (chunks are exactly 11 rows)
    float ring[11][5];
#pragma unroll
    for (int s = 0; s < 11; ++s)
#pragma unroll
        for (int q = 0; q < 5; ++q) ring[s][q] = 0.f;

    float acc = 0.f, accl1 = 0.f, acclw = 0.f;
    const float X = (float)x;

    // input rows r0-5 .. r0+30: 4 chunks of 11 stages, last 8 stages skipped
    for (int c = 0; c < NCHUNK; ++c) {
        __syncthreads();   // previous chunk's spt reads complete
#pragma unroll
        for (int t = 0; t < 11; ++t) {
            int i = 11 * c + t;
            if (i < NIN) {
                int r_in = r0 - 5 + i;
                float pv = 0.f, tv = 0.f;
                if (r_in >= 0 && r_in < HW) {
                    pv = pp[r_in * HW + x];
                    tv = tp[r_in * HW + x];
                }
                spt[t][x + 5] = make_float2(pv, tv);
            }
        }
        __syncthreads();

#pragma unroll
        for (int t = 0; t < 11; ++t) {
            const int i = 11 * c + t;         // runtime (c), slot t compile-time
            if (i >= NIN) continue;           // wave-uniform guard
            const int r_in = r0 - 5 + i;

            // horizontal conv of the 5 moments; capture center tap (k==5)
            float h0 = 0.f, h1 = 0.f, h2 = 0.f, h3 = 0.f, h4 = 0.f;
            float2 center;
#pragma unroll
            for (int k = 0; k < 11; ++k) {
                float2 v = spt[t][x + k];
                if (k == 5) center = v;
                float w = g[k];
                float wp = w * v.x, wt = w * v.y;
                h0 += wp;
                h1 += wt;
                h2 = fmaf(wp, v.x, h2);
                h3 = fmaf(wt, v.y, h3);
                h4 = fmaf(wp, v.y, h4);
            }
            ring[t][0] = h0; ring[t][1] = h1; ring[t][2] = h2;
            ring[t][3] = h3; ring[t][4] = h4;

            // ---- L1 + weighted L1 for input row r_in (each row exactly once)
            if (i >= 5 && i < 5 + STRIP && r_in < HW) {
                float ad = fabsf(center.x - center.y);
                accl1 += ad;
                float wgt = 1.f;
                const int flags = srowflag[i - 5];   // broadcast LDS read
                if (flags) {                  // wave-uniform branch
                    const float* xc = sxc[i - 5];
                    int c0 = 0, c1 = 0, c2 = 0;
#pragma unroll
                    for (int e = 0; e < 6; ++e)   c0 += (X < xc[e]) ? 1 : 0;
#pragma unroll
                    for (int e = 6; e < 12; ++e)  c1 += (X < xc[e]) ? 1 : 0;
#pragma unroll
                    for (int e = 12; e < 24; ++e) c2 += (X < xc[e]) ? 1 : 0;
                    if ((flags & 1) && (c0 & 1) && X >= sbbs[0] && X < sbbs[1]) wgt += 3.f;
                    if ((flags & 2) && (c1 & 1) && X >= sbbs[4] && X < sbbs[5]) wgt += 3.f;
                    if ((flags & 4) && (c2 & 1) && X >= sbbs[8] && X < sbbs[9]) wgt += 2.f;
                }
                acclw += wgt * ad;
            }

            // ---- SSIM output row r_out = r0 + i - 10 ------------------------
            if (i >= 10 && i < 10 + STRIP) {
                const int r_out = r0 + (i - 10);
                if (r_out < HW) {
                    float mux = 0.f, muy = 0.f, exx = 0.f, eyy = 0.f, exy = 0.f;
#pragma unroll
                    for (int j = 0; j < 11; ++j) {
                        const int s = (t + 1 + j) % 11;   // compile-time
                        float w = g[j];
                        mux = fmaf(w, ring[s][0], mux);
                        muy = fmaf(w, ring[s][1], muy);
                        exx = fmaf(w, ring[s][2], exx);
                        eyy = fmaf(w, ring[s][3], eyy);
                        exy = fmaf(w, ring[s][4], exy);
                    }
                    float sx  = exx - mux * mux;
                    float sy  = eyy - muy * muy;
                    float sxy = exy - mux * muy;
                    const float C1 = 1e-4f, C2 = 9e-4f;
                    float num = (2.f * mux * muy + C1) * (2.f * sxy + C2);
                    float den = (mux * mux + muy * muy + C1) * (sx + sy + C2);
                    acc += 0.5f * (1.f - num / (den + 1e-8f));
                }
            }
        }
    }

    // ---- block reduction ---------------------------------------------------
#pragma unroll
    for (int off = 32; off > 0; off >>= 1) {
        acc   += __shfl_down(acc, off, 64);
        accl1 += __shfl_down(accl1, off, 64);
        acclw += __shfl_down(acclw, off, 64);
    }
    if ((x & 63) == 0) {
        int w = x >> 6;
        red[w] = acc; red[4 + w] = accl1; red[8 + w] = acclw;
    }
    __syncthreads();
    if (x == 0) {
        double s = 10.0 * ((double)red[0] + red[1] + red[2]  + red[3])
                 + 10.0 * ((double)red[4] + red[5] + red[6]  + red[7])
                 +  5.0 * ((double)red[8] + red[9] + red[10] + red[11]);
        atomicAdd(&ws[(blockIdx.y * NPLANE + blockIdx.x) & (NSLOT - 1)], s);
    }
}

// ---------------------------------------------------------------------------
__global__ void final_kernel(const double* __restrict__ ws, float* __restrict__ out) {
    double v = ws[threadIdx.x];
#pragma unroll
    for (int off = 32; off > 0; off >>= 1)
        v += __shfl_down(v, off, 64);
    if (threadIdx.x == 0) {
        const double denom = (double)NIMG * NCH * HW * HW;
        out[0] = (float)(v / denom);
    }
}

// ---------------------------------------------------------------------------
extern "C" void kernel_launch(void* const* d_in, const int* in_sizes, int n_in,
                              void* d_out, int out_size, void* d_ws, size_t ws_size,
                              hipStream_t stream)
{
    const float* pred   = (const float*)d_in[0];
    const float* target = (const float*)d_in[1];
    const float* lmk    = (const float*)d_in[2];
    float* out  = (float*)d_out;
    double* ws  = (double*)d_ws;

    hipLaunchKernelGGL(zero_ws_kernel, dim3(1), dim3(64), 0, stream, ws);
    hipLaunchKernelGGL(fused_kernel, dim3(NPLANE, NSTRIP), dim3(256), 0, stream,
                       pred, target, lmk, ws);
    hipLaunchKernelGGL(final_kernel, dim3(1), dim3(64), 0, stream, ws, out);
}

// Round 7
// 162.665 us; speedup vs baseline: 4.1019x; 1.0424x over previous
//
#include <hip/hip_runtime.h>
#include <cmath>

#define HW 256
#define NIMG 48
#define NCH 3
#define NPLANE (NIMG * NCH)
#define STRIP 37          // output rows per block
#define NSTRIP 7          // 7*37 = 259 >= 256
#define COLS 128          // output cols per block
#define NCB 2             // col tiles; grid = 144*7*2 = 2016 = 7.875/CU
#define NIN (STRIP + 10)  // 47 input rows per block
#define NCHUNK 5          // ceil(47/11)
#define NSLOT 64          // ws accumulator slots

// ws doubles: ws[0..63] partial sums of (10*d + 10*l1 + 5*lw)
__global__ void zero_ws_kernel(double* ws) {
    if (threadIdx.x < NSLOT) ws[threadIdx.x] = 0.0;
}

// ---------------------------------------------------------------------------
// Fused SSIM + L1 + weighted-L1. One block = 37-row x 128-col tile.
//
// OCCUPANCY MODEL (rounds 0-6, journal): waves/SIMD = min(8, 256/VGPR).
// At VGPR=64 (the no-spill floor for the 55-reg moment ring) we are pinned
// at 4 waves/SIMD = 16 waves/CU; explicit caps to go lower spill (r1/r4/r5).
// Round 6 proved more *blocks* at 4-wave cap gains nothing: all 16 waves in
// 4 blocks stall together at each block's staging barrier (vmcnt(0) drain).
// THIS round: same 16 waves/CU but split into 8 independent 2-wave blocks
// (128-col tiles) -> 8 barrier domains; one block's staging drain overlaps
// 7 other blocks' compute. Col-halo costs only 138/128 = +8% staging.
// Grid 2016 = 7.875 blocks/CU = one residency round at the 8-block cap.
// Body is the verbatim round-2/6 no-spill structure (CH=11 runtime chunk
// loop, plain __launch_bounds__, srowflag hot path).
// Round-3 lesson: barrier between sbbs writes (x<3) and cross-thread reads.
// ---------------------------------------------------------------------------
__launch_bounds__(128)
__global__ void fused_kernel(const float* __restrict__ pred,
                             const float* __restrict__ target,
                             const float* __restrict__ lmk,
                             double* __restrict__ ws)
{
    const int plane = blockIdx.x;          // n*3 + c
    const int n     = plane / 3;
    const int r0    = blockIdx.y * STRIP;
    const int c0    = blockIdx.z * COLS;
    const int x     = threadIdx.x;

    __shared__ float2 spt[11][COLS + 10];  // (p,t) rows incl. 5-col halos
    __shared__ float  sxc[STRIP][24];      // crossing x per (row, edge)
    __shared__ int    srowflag[STRIP];     // bit p: poly p valid && row in y-range
    __shared__ float  slm[48];             // landmarks 36..59 (x,y)
    __shared__ float  sbbs[12];            // per poly: xmin,xmax,ymin,ymax
    __shared__ float  svalids[3];

    // Gaussian weights (same fp32 math as reference)
    float g[11];
    {
        float gs = 0.f;
#pragma unroll
        for (int i = 0; i < 11; ++i) {
            float c = (float)i - 5.0f;
            g[i] = expf(-c * c / 4.5f);
            gs += g[i];
        }
#pragma unroll
        for (int i = 0; i < 11; ++i) g[i] /= gs;
    }

    // ---- prologue ----------------------------------------------------------
    if (x < 48) slm[x] = lmk[n * 136 + 72 + x];
    __syncthreads();   // slm ready

    if (x < 3) {
        const int s0 = (x == 0) ? 0 : (x == 1) ? 6 : 12;
        const int L  = (x == 2) ? 12 : 6;
        float xmn = 3e38f, xmx = -3e38f, ymn = 3e38f, ymx = -3e38f;
        for (int i = 0; i < L; ++i) {
            float px = slm[2 * (s0 + i)], py = slm[2 * (s0 + i) + 1];
            xmn = fminf(xmn, px); xmx = fmaxf(xmx, px);
            ymn = fminf(ymn, py); ymx = fmaxf(ymx, py);
        }
        xmn = floorf(xmn); xmx = floorf(xmx); ymn = floorf(ymn); ymx = floorf(ymx);
        sbbs[4 * x + 0] = xmn; sbbs[4 * x + 1] = xmx;
        sbbs[4 * x + 2] = ymn; sbbs[4 * x + 3] = ymx;
        svalids[x] = (xmn >= 0.f && ymn >= 0.f && xmx < 256.f && ymx < 256.f) ? 1.f : 0.f;
    }

#pragma unroll
    for (int u = 0; u < (STRIP * 24 + 127) / 128; ++u) {
        int idx = x + 128 * u;
        if (idx < STRIP * 24) {
            int r = idx / 24, e = idx - r * 24;
            float Y = (float)(r0 + r);
            const int s0 = (e < 6) ? 0 : (e < 12) ? 6 : 12;
            const int L  = (e < 12) ? 6 : 12;
            int il = e - s0;
            int i2 = (il + 1 == L) ? 0 : il + 1;
            float x1 = slm[2 * (s0 + il)], y1 = slm[2 * (s0 + il) + 1];
            float x2 = slm[2 * (s0 + i2)], y2 = slm[2 * (s0 + i2) + 1];
            bool crossing = (y1 > Y) != (y2 > Y);
            // exact reference fp32 expression order
            float xc = (x2 - x1) * (Y - y1) / (y2 - y1 + 1e-6f) + x1;
            sxc[r][e] = crossing ? xc : -3e38f;
        }
    }
    __syncthreads();   // sbbs/svalids visible to all (round-3 fix); sxc ready

    if (x < STRIP) {
        float Y = (float)(r0 + x);
        int f = 0;
        if (svalids[0] != 0.f && Y >= sbbs[2]  && Y < sbbs[3])  f |= 1;
        if (svalids[1] != 0.f && Y >= sbbs[6]  && Y < sbbs[7])  f |= 2;
        if (svalids[2] != 0.f && Y >= sbbs[10] && Y < sbbs[11]) f |= 4;
        srowflag[x] = f;
    }
    __syncthreads();   // srowflag ready

    const float* __restrict__ pp = pred   + (size_t)plane * (HW * HW);
    const float* __restrict__ tp = target + (size_t)plane * (HW * HW);

    // h-conv moment ring: slot = t (chunks are exactly 11 rows)
    float ring[11][5];
#pragma unroll
    for (int s = 0; s < 11; ++s)
#pragma unroll
        for (int q = 0; q < 5; ++q) ring[s][q] = 0.f;

    float acc = 0.f, accl1 = 0.f, acclw = 0.f;
    const float X = (float)(c0 + x);

    // input rows r0-5 .. r0+41: 5 chunks of 11 stages, last 8 stages skipped
    for (int c = 0; c < NCHUNK; ++c) {
        __syncthreads();   // previous chunk's spt reads complete
#pragma unroll
        for (int t = 0; t < 11; ++t) {
            int i = 11 * c + t;
            if (i < NIN) {
                int r_in = r0 - 5 + i;
                // left 128 entries: global col gc = c0-5+x in [-5, 250]
                {
                    int gc = c0 - 5 + x;
                    float pv = 0.f, tv = 0.f;
                    if (r_in >= 0 && r_in < HW && gc >= 0) {
                        pv = pp[r_in * HW + gc];
                        tv = tp[r_in * HW + gc];
                    }
                    spt[t][x] = make_float2(pv, tv);
                }
                // right 10 entries: gc = c0+123+x in [123,133) / [251,261)
                if (x < 10) {
                    int gc = c0 + 123 + x;
                    float pv = 0.f, tv = 0.f;
                    if (r_in >= 0 && r_in < HW && gc < HW) {
                        pv = pp[r_in * HW + gc];
                        tv = tp[r_in * HW + gc];
                    }
                    spt[t][COLS + x] = make_float2(pv, tv);
                }
            }
        }
        __syncthreads();

#pragma unroll
        for (int t = 0; t < 11; ++t) {
            const int i = 11 * c + t;         // runtime (c), slot t compile-time
            if (i >= NIN) continue;           // wave-uniform guard
            const int r_in = r0 - 5 + i;

            // horizontal conv of the 5 moments; capture center tap (k==5)
            float h0 = 0.f, h1 = 0.f, h2 = 0.f, h3 = 0.f, h4 = 0.f;
            float2 center;
#pragma unroll
            for (int k = 0; k < 11; ++k) {
                float2 v = spt[t][x + k];
                if (k == 5) center = v;
                float w = g[k];
                float wp = w * v.x, wt = w * v.y;
                h0 += wp;
                h1 += wt;
                h2 = fmaf(wp, v.x, h2);
                h3 = fmaf(wt, v.y, h3);
                h4 = fmaf(wp, v.y, h4);
            }
            ring[t][0] = h0; ring[t][1] = h1; ring[t][2] = h2;
            ring[t][3] = h3; ring[t][4] = h4;

            // ---- L1 + weighted L1 for input row r_in (each row exactly once)
            if (i >= 5 && i < 5 + STRIP && r_in < HW) {
                float ad = fabsf(center.x - center.y);
                accl1 += ad;
                float wgt = 1.f;
                const int flags = srowflag[i - 5];   // broadcast LDS read
                if (flags) {                  // wave-uniform branch
                    const float* xc = sxc[i - 5];
                    int c0c = 0, c1c = 0, c2c = 0;
#pragma unroll
                    for (int e = 0; e < 6; ++e)   c0c += (X < xc[e]) ? 1 : 0;
#pragma unroll
                    for (int e = 6; e < 12; ++e)  c1c += (X < xc[e]) ? 1 : 0;
#pragma unroll
                    for (int e = 12; e < 24; ++e) c2c += (X < xc[e]) ? 1 : 0;
                    if ((flags & 1) && (c0c & 1) && X >= sbbs[0] && X < sbbs[1]) wgt += 3.f;
                    if ((flags & 2) && (c1c & 1) && X >= sbbs[4] && X < sbbs[5]) wgt += 3.f;
                    if ((flags & 4) && (c2c & 1) && X >= sbbs[8] && X < sbbs[9]) wgt += 2.f;
                }
                acclw += wgt * ad;
            }

            // ---- SSIM output row r_out = r0 + i - 10 ------------------------
            if (i >= 10 && i < 10 + STRIP) {
                const int r_out = r0 + (i - 10);
                if (r_out < HW) {
                    float mux = 0.f, muy = 0.f, exx = 0.f, eyy = 0.f, exy = 0.f;
#pragma unroll
                    for (int j = 0; j < 11; ++j) {
                        const int s = (t + 1 + j) % 11;   // compile-time
                        float w = g[j];
                        mux = fmaf(w, ring[s][0], mux);
                        muy = fmaf(w, ring[s][1], muy);
                        exx = fmaf(w, ring[s][2], exx);
                        eyy = fmaf(w, ring[s][3], eyy);
                        exy = fmaf(w, ring[s][4], exy);
                    }
                    float sx  = exx - mux * mux;
                    float sy  = eyy - muy * muy;
                    float sxy = exy - mux * muy;
                    const float C1 = 1e-4f, C2 = 9e-4f;
                    float num = (2.f * mux * muy + C1) * (2.f * sxy + C2);
                    float den = (mux * mux + muy * muy + C1) * (sx + sy + C2);
                    acc += 0.5f * (1.f - num / (den + 1e-8f));
                }
            }
        }
    }

    // ---- reduction: per-wave shuffle, one atomic per wave ------------------
#pragma unroll
    for (int off = 32; off > 0; off >>= 1) {
        acc   += __shfl_down(acc, off, 64);
        accl1 += __shfl_down(accl1, off, 64);
        acclw += __shfl_down(acclw, off, 64);
    }
    if ((x & 63) == 0) {
        double s = 10.0 * (double)acc + 10.0 * (double)accl1 + 5.0 * (double)acclw;
        int bid = (blockIdx.z * NSTRIP + blockIdx.y) * NPLANE + blockIdx.x;
        atomicAdd(&ws[(2 * bid + (x >> 6)) & (NSLOT - 1)], s);
    }
}

// ---------------------------------------------------------------------------
__global__ void final_kernel(const double* __restrict__ ws, float* __restrict__ out) {
    double v = ws[threadIdx.x];
#pragma unroll
    for (int off = 32; off > 0; off >>= 1)
        v += __shfl_down(v, off, 64);
    if (threadIdx.x == 0) {
        const double denom = (double)NIMG * NCH * HW * HW;
        out[0] = (float)(v / denom);
    }
}

// ---------------------------------------------------------------------------
extern "C" void kernel_launch(void* const* d_in, const int* in_sizes, int n_in,
                              void* d_out, int out_size, void* d_ws, size_t ws_size,
                              hipStream_t stream)
{
    const float* pred   = (const float*)d_in[0];
    const float* target = (const float*)d_in[1];
    const float* lmk    = (const float*)d_in[2];
    float* out  = (float*)d_out;
    double* ws  = (double*)d_ws;

    hipLaunchKernelGGL(zero_ws_kernel, dim3(1), dim3(64), 0, stream, ws);
    hipLaunchKernelGGL(fused_kernel, dim3(NPLANE, NSTRIP, NCB), dim3(128), 0, stream,
                       pred, target, lmk, ws);
    hipLaunchKernelGGL(final_kernel, dim3(1), dim3(64), 0, stream, ws, out);
}

// Round 8
// 152.974 us; speedup vs baseline: 4.3618x; 1.0633x over previous
//
#include <hip/hip_runtime.h>
#include <cmath>

#define HW 256
#define NIMG 48
#define NCH 3
#define NPLANE (NIMG * NCH)
#define STRIP 37          // output rows per block; grid 144*7 = 1008 <= 1024
#define NSTRIP 7          // one residency round at 4 blocks/CU (VGPR=64 band)
#define NIN (STRIP + 10)  // 47 input rows per block
#define CHUNK 22          // even multiple of 11: i%11 and i%2 compile-time
#define NCHUNK 3          // 66 slots; runtime guards prune past i=47
#define NSLOT 64          // ws accumulator slots

// ws doubles: ws[0..63] partial sums of (10*d + 10*l1 + 5*lw)
__global__ void zero_ws_kernel(double* ws) {
    if (threadIdx.x < NSLOT) ws[threadIdx.x] = 0.0;
}

// ---------------------------------------------------------------------------
// Fused SSIM + L1 + weighted-L1, V-FIRST formulation (round 8).
//
// Rounds 2/6/7 invariant: dur = VALU_work / VALUBusy with VALUBusy pinned at
// ~55% -- per-wave stalls hit all lockstep waves at once: (a) staging loads
// consumed immediately after issue, (b) __syncthreads' vmcnt(0) drain.
// This version: thread x owns column x. Vertical 11-tap conv runs on the
// thread's own raw-row register ring (22 VGPR, was 55). Only the 5
// v-convolved moments pass through LDS (float4+float, conflict-free b128),
// double-buffered by row parity; h-conv reads 11 neighbor cols. One RAW
// s_barrier + lgkmcnt(0) per row -- vmcnt deliberately NOT drained, so the
// depth-2 register prefetch (row i+2 issued at iter i) survives barriers.
// Zero column redundancy; halo rows are load-only (no h-conv on halo).
// Round-1/4/5 lesson: no launch_bounds VGPR caps (spills). Round-3 lesson:
// barrier between x<3 sbbs writes and cross-thread reads.
// ---------------------------------------------------------------------------
__launch_bounds__(256)
__global__ void fused_kernel(const float* __restrict__ pred,
                             const float* __restrict__ target,
                             const float* __restrict__ lmk,
                             double* __restrict__ ws)
{
    const int plane = blockIdx.x;          // n*3 + c
    const int n     = plane / 3;
    const int r0    = blockIdx.y * STRIP;
    const int x     = threadIdx.x;

    __shared__ float4 mva[2][HW + 10];     // v-moments: mux,muy,exx,eyy (5-col pads)
    __shared__ float  mvb[2][HW + 10];     // v-moment: exy
    __shared__ float  sxc[STRIP][24];      // crossing x per (row, edge)
    __shared__ int    srowflag[STRIP];     // bit p: poly p valid && row in y-range
    __shared__ float  slm[48];             // landmarks 36..59 (x,y)
    __shared__ float  sbbs[12];            // per poly: xmin,xmax,ymin,ymax
    __shared__ float  svalids[3];
    __shared__ float  red[12];

    // Gaussian weights, symmetric: keep only 6 (g[j] == g[10-j]) to save VGPRs
    float g6[6];
    {
        float gg[11]; float gs = 0.f;
#pragma unroll
        for (int q = 0; q < 11; ++q) {
            float c = (float)q - 5.0f;
            gg[q] = expf(-c * c / 4.5f);
            gs += gg[q];
        }
#pragma unroll
        for (int q = 0; q < 6; ++q) g6[q] = gg[q] / gs;
    }
#define GW(j) g6[(j) < 6 ? (j) : 10 - (j)]   // j is always compile-time

    // ---- prologue ----------------------------------------------------------
    if (x < 48) slm[x] = lmk[n * 136 + 72 + x];
    if (x < 5) {
        const float4 z4 = make_float4(0.f, 0.f, 0.f, 0.f);
        mva[0][x] = z4; mva[0][261 + x] = z4;
        mva[1][x] = z4; mva[1][261 + x] = z4;
        mvb[0][x] = 0.f; mvb[0][261 + x] = 0.f;
        mvb[1][x] = 0.f; mvb[1][261 + x] = 0.f;
    }
    __syncthreads();   // slm ready

    if (x < 3) {
        const int s0 = (x == 0) ? 0 : (x == 1) ? 6 : 12;
        const int L  = (x == 2) ? 12 : 6;
        float xmn = 3e38f, xmx = -3e38f, ymn = 3e38f, ymx = -3e38f;
        for (int q = 0; q < L; ++q) {
            float px = slm[2 * (s0 + q)], py = slm[2 * (s0 + q) + 1];
            xmn = fminf(xmn, px); xmx = fmaxf(xmx, px);
            ymn = fminf(ymn, py); ymx = fmaxf(ymx, py);
        }
        xmn = floorf(xmn); xmx = floorf(xmx); ymn = floorf(ymn); ymx = floorf(ymx);
        sbbs[4 * x + 0] = xmn; sbbs[4 * x + 1] = xmx;
        sbbs[4 * x + 2] = ymn; sbbs[4 * x + 3] = ymx;
        svalids[x] = (xmn >= 0.f && ymn >= 0.f && xmx < 256.f && ymx < 256.f) ? 1.f : 0.f;
    }

#pragma unroll
    for (int u = 0; u < (STRIP * 24 + 255) / 256; ++u) {
        int idx = x + 256 * u;
        if (idx < STRIP * 24) {
            int r = idx / 24, e = idx - r * 24;
            float Y = (float)(r0 + r);
            const int s0 = (e < 6) ? 0 : (e < 12) ? 6 : 12;
            const int L  = (e < 12) ? 6 : 12;
            int il = e - s0;
            int i2 = (il + 1 == L) ? 0 : il + 1;
            float x1 = slm[2 * (s0 + il)], y1 = slm[2 * (s0 + il) + 1];
            float x2 = slm[2 * (s0 + i2)], y2 = slm[2 * (s0 + i2) + 1];
            bool crossing = (y1 > Y) != (y2 > Y);
            // exact reference fp32 expression order
            float xc = (x2 - x1) * (Y - y1) / (y2 - y1 + 1e-6f) + x1;
            sxc[r][e] = crossing ? xc : -3e38f;
        }
    }
    __syncthreads();   // sbbs/svalids visible to all (round-3 fix); sxc ready

    if (x < STRIP) {
        float Y = (float)(r0 + x);
        int f = 0;
        if (svalids[0] != 0.f && Y >= sbbs[2]  && Y < sbbs[3])  f |= 1;
        if (svalids[1] != 0.f && Y >= sbbs[6]  && Y < sbbs[7])  f |= 2;
        if (svalids[2] != 0.f && Y >= sbbs[10] && Y < sbbs[11]) f |= 4;
        srowflag[x] = f;
    }
    __syncthreads();   // srowflag ready; mva/mvb pads ready

    // column-x base pointers (coalesced across threads)
    const float* __restrict__ pp = pred   + (size_t)plane * (HW * HW) + x;
    const float* __restrict__ tp = target + (size_t)plane * (HW * HW) + x;

    // raw-row register ring (22 VGPR) + depth-2 prefetch pair
    float rp[11], rt[11];
    float pfap, pfat, pfbp, pfbt;
    {   // warmup: rows i=0 (r0-5) and i=1 (r0-4); r0+? always < HW here
        int ra = r0 - 5;
        bool va = (ra >= 0);
        pfap = va ? pp[(size_t)ra * HW] : 0.f;
        pfat = va ? tp[(size_t)ra * HW] : 0.f;
        int rb = r0 - 4;
        bool vb = (rb >= 0);
        pfbp = vb ? pp[(size_t)rb * HW] : 0.f;
        pfbt = vb ? tp[(size_t)rb * HW] : 0.f;
    }

    float acc = 0.f, accl1 = 0.f, acclw = 0.f;
    const float X = (float)x;

    for (int c = 0; c < NCHUNK; ++c) {
#pragma unroll
        for (int t = 0; t < CHUNK; ++t) {
            const int i  = CHUNK * c + t;   // runtime (c), t compile-time
            const int sr = t % 11;          // ring slot of row i (22c % 11 == 0)

            if (i < NIN) {
                // consume prefetch (issued 2 iters ago) into the ring
                if ((t & 1) == 0) { rp[sr] = pfap; rt[sr] = pfat; }
                else              { rp[sr] = pfbp; rt[sr] = pfbt; }
                // issue load for row i+2 (waited at use, 2 iters later)
                {
                    int rin2 = r0 - 3 + i;
                    bool v = (i + 2 < NIN) && (rin2 >= 0) && (rin2 < HW);
                    float lp = 0.f, lt = 0.f;
                    if (v) {
                        lp = pp[(size_t)rin2 * HW];
                        lt = tp[(size_t)rin2 * HW];
                    }
                    if ((t & 1) == 0) { pfap = lp; pfat = lt; }
                    else              { pfbp = lp; pfbt = lt; }
                }

                // ---- L1 + weighted L1 for raw row r_in = r0-5+i ------------
                if (i >= 5 && i < 5 + STRIP) {      // runtime uniform
                    int r_in = r0 - 5 + i;
                    if (r_in < HW) {
                        float ad = fabsf(rp[sr] - rt[sr]);
                        accl1 += ad;
                        float wgt = 1.f;
                        const int flags = srowflag[i - 5];   // broadcast read
                        if (flags) {                 // wave-uniform branch
                            const float* xc = sxc[i - 5];
                            int c0 = 0, c1 = 0, c2 = 0;
#pragma unroll
                            for (int e = 0; e < 6; ++e)   c0 += (X < xc[e]) ? 1 : 0;
#pragma unroll
                            for (int e = 6; e < 12; ++e)  c1 += (X < xc[e]) ? 1 : 0;
#pragma unroll
                            for (int e = 12; e < 24; ++e) c2 += (X < xc[e]) ? 1 : 0;
                            if ((flags & 1) && (c0 & 1) && X >= sbbs[0] && X < sbbs[1]) wgt += 3.f;
                            if ((flags & 2) && (c1 & 1) && X >= sbbs[4] && X < sbbs[5]) wgt += 3.f;
                            if ((flags & 4) && (c2 & 1) && X >= sbbs[8] && X < sbbs[9]) wgt += 2.f;
                        }
                        acclw += wgt * ad;
                    }
                }
            }

            // ---- vertical conv -> moment row r = r0 + i - 10 ---------------
            if (i >= 10 && i < 10 + STRIP) {        // runtime uniform
                int r = r0 + i - 10;
                if (r < HW) {
                    float mux = 0.f, muy = 0.f, exx = 0.f, eyy = 0.f, exy = 0.f;
#pragma unroll
                    for (int j = 0; j < 11; ++j) {
                        const int s = (t + 1 + j) % 11;   // compile-time
                        float w = GW(j);
                        float p = rp[s], q = rt[s];
                        float wp = w * p, wt = w * q;
                        mux += wp; muy += wt;
                        exx = fmaf(wp, p, exx);
                        eyy = fmaf(wt, q, eyy);
                        exy = fmaf(wp, q, exy);
                    }
                    mva[t & 1][x + 5] = make_float4(mux, muy, exx, eyy);
                    mvb[t & 1][x + 5] = exy;        // parity (i-10)&1 == t&1
                }
            }

            // ---- horizontal conv + SSIM for row r' = r0 + i - 11 -----------
            if (i >= 11 && i < 11 + STRIP) {        // runtime uniform
                int rr = r0 + i - 11;
                if (rr < HW) {
                    const int b = (t + 1) & 1;      // (i-11)&1, compile-time
                    float Mx = 0.f, My = 0.f, Exx = 0.f, Eyy = 0.f, Exy = 0.f;
#pragma unroll
                    for (int k = 0; k < 11; ++k) {
                        float w = GW(k);
                        float4 m4 = mva[b][x + k];
                        float  m1 = mvb[b][x + k];
                        Mx  = fmaf(w, m4.x, Mx);
                        My  = fmaf(w, m4.y, My);
                        Exx = fmaf(w, m4.z, Exx);
                        Eyy = fmaf(w, m4.w, Eyy);
                        Exy = fmaf(w, m1,  Exy);
                    }
                    float sx  = Exx - Mx * Mx;
                    float sy  = Eyy - My * My;
                    float sxy = Exy - Mx * My;
                    const float C1 = 1e-4f, C2 = 9e-4f;
                    float num = (2.f * Mx * My + C1) * (2.f * sxy + C2);
                    float den = (Mx * Mx + My * My + C1) * (sx + sy + C2);
                    acc += 0.5f * (1.f - num / (den + 1e-8f));
                }
            }

            // raw barrier: drain LDS (moment writes visible) but NOT vmcnt,
            // so the depth-2 prefetch loads stay in flight across it.
            asm volatile("s_waitcnt lgkmcnt(0)" ::: "memory");
            __builtin_amdgcn_s_barrier();
        }
    }

    // ---- block reduction ---------------------------------------------------
#pragma unroll
    for (int off = 32; off > 0; off >>= 1) {
        acc   += __shfl_down(acc, off, 64);
        accl1 += __shfl_down(accl1, off, 64);
        acclw += __shfl_down(acclw, off, 64);
    }
    if ((x & 63) == 0) {
        int w = x >> 6;
        red[w] = acc; red[4 + w] = accl1; red[8 + w] = acclw;
    }
    __syncthreads();
    if (x == 0) {
        double s = 10.0 * ((double)red[0] + red[1] + red[2]  + red[3])
                 + 10.0 * ((double)red[4] + red[5] + red[6]  + red[7])
                 +  5.0 * ((double)red[8] + red[9] + red[10] + red[11]);
        atomicAdd(&ws[(blockIdx.y * NPLANE + blockIdx.x) & (NSLOT - 1)], s);
    }
}

// ---------------------------------------------------------------------------
__global__ void final_kernel(const double* __restrict__ ws, float* __restrict__ out) {
    double v = ws[threadIdx.x];
#pragma unroll
    for (int off = 32; off > 0; off >>= 1)
        v += __shfl_down(v, off, 64);
    if (threadIdx.x == 0) {
        const double denom = (double)NIMG * NCH * HW * HW;
        out[0] = (float)(v / denom);
    }
}

// ---------------------------------------------------------------------------
extern "C" void kernel_launch(void* const* d_in, const int* in_sizes, int n_in,
                              void* d_out, int out_size, void* d_ws, size_t ws_size,
                              hipStream_t stream)
{
    const float* pred   = (const float*)d_in[0];
    const float* target = (const float*)d_in[1];
    const float* lmk    = (const float*)d_in[2];
    float* out  = (float*)d_out;
    double* ws  = (double*)d_ws;

    hipLaunchKernelGGL(zero_ws_kernel, dim3(1), dim3(64), 0, stream, ws);
    hipLaunchKernelGGL(fused_kernel, dim3(NPLANE, NSTRIP), dim3(256), 0, stream,
                       pred, target, lmk, ws);
    hipLaunchKernelGGL(final_kernel, dim3(1), dim3(64), 0, stream, ws, out);
}